// Round 9
// baseline (1293.939 us; speedup 1.0000x reference)
//
#include <hip/hip_runtime.h>
#include <hip/hip_bf16.h>

#define N_NODES 100000
#define N_EDGES 1600000
#define DD 128
#define N_GRAPHS 512
#define BN_EPS 1e-5f
#define NTILES 1563            // ceil(100000/64)

typedef unsigned int u32;
typedef unsigned char u8;
typedef __bf16 bf16_t;
typedef __bf16 bf16x4 __attribute__((ext_vector_type(4)));
typedef __bf16 bf16x8 __attribute__((ext_vector_type(8)));
typedef float f32x4 __attribute__((ext_vector_type(4)));

__device__ __forceinline__ float bflo2f(u32 u) {
    union { u32 i; float f; } x; x.i = u << 16; return x.f;
}
__device__ __forceinline__ float bfhi2f(u32 u) {
    union { u32 i; float f; } x; x.i = u & 0xffff0000u; return x.f;
}
// accumulate 8 bf16 features (uint4) into a[0..7]
__device__ __forceinline__ void accbf(float* a, uint4 r) {
    a[0] += bflo2f(r.x); a[1] += bfhi2f(r.x);
    a[2] += bflo2f(r.y); a[3] += bfhi2f(r.y);
    a[4] += bflo2f(r.z); a[5] += bfhi2f(r.z);
    a[6] += bflo2f(r.w); a[7] += bfhi2f(r.w);
}
// accumulate 8 bf16 features scaled by c
__device__ __forceinline__ void accbf_s(float* a, uint4 r, float c) {
    a[0] += c * bflo2f(r.x); a[1] += c * bfhi2f(r.x);
    a[2] += c * bflo2f(r.y); a[3] += c * bfhi2f(r.y);
    a[4] += c * bflo2f(r.z); a[5] += c * bfhi2f(r.z);
    a[6] += c * bflo2f(r.w); a[7] += c * bfhi2f(r.w);
}
// accumulate 8 uint8 features (uint2) scaled by s into a[0..7]
__device__ __forceinline__ void acc8u(float* a, uint2 q, float s) {
#pragma unroll
    for (int j = 0; j < 4; ++j)
        a[j] += s * (float)((q.x >> (8 * j)) & 0xffu);
#pragma unroll
    for (int j = 0; j < 4; ++j)
        a[4 + j] += s * (float)((q.y >> (8 * j)) & 0xffu);
}
__device__ __forceinline__ u32 pack4u(float v0, float v1, float v2, float v3, float inv) {
    u32 q0 = (u32)fminf(rintf(v0 * inv), 255.f);
    u32 q1 = (u32)fminf(rintf(v1 * inv), 255.f);
    u32 q2 = (u32)fminf(rintf(v2 * inv), 255.f);
    u32 q3 = (u32)fminf(rintf(v3 * inv), 255.f);
    return q0 | (q1 << 8) | (q2 << 16) | (q3 << 24);
}

// ---------------- utility kernels ----------------

__global__ void k_zero(float4* p, int n) {
    float4 z = make_float4(0.f, 0.f, 0.f, 0.f);
    for (int i = blockIdx.x * blockDim.x + threadIdx.x; i < n; i += gridDim.x * blockDim.x)
        p[i] = z;
}

__global__ void k_hist(const int* __restrict__ dst, int* __restrict__ deg) {
    for (int e = blockIdx.x * blockDim.x + threadIdx.x; e < N_EDGES; e += gridDim.x * blockDim.x)
        atomicAdd(&deg[dst[e]], 1);
}

// single block: exclusive scan of padded degrees ((deg+15)&~15) -> poffs, cursor
__global__ void k_scan(const int* __restrict__ deg, int* __restrict__ poffs, int* __restrict__ cursor) {
    __shared__ int ps[1024];
    int t = threadIdx.x;
    int s = 0;
    if (t < 1000) {
        const int4* d4 = (const int4*)(deg + t * 100);
        for (int i = 0; i < 25; ++i) {
            int4 v = d4[i];
            s += ((v.x + 15) & ~15) + ((v.y + 15) & ~15) + ((v.z + 15) & ~15) + ((v.w + 15) & ~15);
        }
    }
    ps[t] = s;
    __syncthreads();
    for (int d2 = 1; d2 < 1024; d2 <<= 1) {
        int v = (t >= d2) ? ps[t - d2] : 0;
        __syncthreads();
        ps[t] += v;
        __syncthreads();
    }
    int run = ps[t] - s;
    if (t < 1000) {
        for (int i = 0; i < 100; ++i) {
            int idx = t * 100 + i;
            poffs[idx] = run; cursor[idx] = run;
            run += (deg[idx] + 15) & ~15;
        }
    }
    if (t == 1023) poffs[N_NODES] = ps[1023];
}

__global__ void k_fill(const int* __restrict__ src, const int* __restrict__ dst,
                       int* __restrict__ cursor, int* __restrict__ csr) {
    for (int e = blockIdx.x * blockDim.x + threadIdx.x; e < N_EDGES; e += gridDim.x * blockDim.x) {
        int pos = atomicAdd(&cursor[dst[e]], 1);
        csr[pos] = src[e];
    }
}

// fill pad slots with the DEST node's own index; gather subtracts the
// overcount via the self-term coefficient (1 - #pads).
__global__ void k_pad(const int* __restrict__ deg, const int* __restrict__ poffs,
                      int* __restrict__ csr) {
    int t = blockIdx.x * blockDim.x + threadIdx.x;
    if (t >= N_NODES * 16) return;
    int n = t >> 4, j = t & 15;
    int s = poffs[n] + deg[n];
    if (s + j < poffs[n + 1]) csr[s + j] = n;
}

__global__ void k_cvt(const float* __restrict__ x, bf16_t* __restrict__ xb) {
    const int n4 = N_NODES * DD / 4;
    const float4* x4 = (const float4*)x;
    bf16x4* o4 = (bf16x4*)xb;
    for (int i = blockIdx.x * blockDim.x + threadIdx.x; i < n4; i += gridDim.x * blockDim.x) {
        float4 v = x4[i];
        bf16x4 o;
        o.x = (bf16_t)v.x; o.y = (bf16_t)v.y; o.z = (bf16_t)v.z; o.w = (bf16_t)v.w;
        o4[i] = o;
    }
}

// Pre-shuffle the 6 weight matrices into exact MFMA B-fragment order (bf16).
__global__ void k_shufw(const float* __restrict__ W1s, const float* __restrict__ W2s,
                        bf16_t* __restrict__ wshuf) {
    int t = blockIdx.x * blockDim.x + threadIdx.x;
    if (t >= 6 * 16384) return;
    int g  = t >> 14;
    int r  = t & 16383;
    int j  = r & 7;
    int L  = (r >> 3) & 63;
    int nt = (r >> 9) & 7;
    int ks = r >> 12;
    int l  = g >> 1;
    const float* src = (g & 1) ? (W2s + l * 16384) : (W1s + l * 16384);
    int k = ks * 32 + (L >> 4) * 8 + j;
    int n = nt * 16 + (L & 15);
    wshuf[t] = (bf16_t)src[k * DD + n];
}

__global__ void k_aff_init(float* __restrict__ ss) {
    int f = threadIdx.x;
    if (f < DD) { ss[f] = 1.0f; ss[DD + f] = 0.0f; }
}

__global__ void k_aff_update(const float* __restrict__ stats, const float* __restrict__ gamma,
                             const float* __restrict__ beta, float* __restrict__ scale,
                             float* __restrict__ shift) {
    int f = threadIdx.x;
    if (f < DD) {
        float mu  = stats[f] * (1.0f / N_NODES);
        float var = stats[DD + f] * (1.0f / N_NODES) - mu * mu;
        float inv = rsqrtf(var + BN_EPS);
        float sc  = gamma[f] * inv;
        scale[f] = sc;
        shift[f] = beta[f] - mu * sc;
    }
}

__global__ void k_gbounds(const int* __restrict__ batch, int* __restrict__ gstart) {
    int i = blockIdx.x * blockDim.x + threadIdx.x;
    if (i >= N_NODES) return;
    int b = batch[i];
    int bp = (i == 0) ? -1 : batch[i - 1];
    for (int g = bp + 1; g <= b; ++g) gstart[g] = i;
    if (i == N_NODES - 1)
        for (int g = b + 1; g <= N_GRAPHS; ++g) gstart[g] = N_NODES;
}

// ---------------- fused GIN layer ----------------
// block = 256 (4 waves), 64 nodes. Gather: wave per node; per 16-edge
// iteration each quarter-sub loads an int4 of indices (prefetched one
// iteration ahead) then issues 4 INDEPENDENT row loads (+4 scale loads for
// u8) — deep MLP per chain step. Edge lists padded to x16 with the node's
// own index; self term applied with coefficient (1 - #pads) to correct.
// Output always uint8 + per-row scale.
template<bool IN_U8>
__global__ __launch_bounds__(256, 8) void k_layer(
    const bf16_t* __restrict__ xb,
    const u8* __restrict__ x8, const float* __restrict__ xsc,
    u8* __restrict__ y8, float* __restrict__ ysc,
    const int* __restrict__ poffs, const int* __restrict__ csr,
    const int* __restrict__ deg,
    const float* __restrict__ scale, const float* __restrict__ shift,
    const bf16_t* __restrict__ w1s, const bf16_t* __restrict__ w2s,
    const float* __restrict__ b1, const float* __restrict__ b2,
    float* __restrict__ stats)
{
    __shared__ __align__(16) bf16_t tile[64 * 136];

    const int tid  = threadIdx.x;
    const int w    = tid >> 6;
    const int lane = tid & 63;
    const int base = blockIdx.x * 64;
    const int sub  = lane >> 4;
    const int fl   = lane & 15;

    const uint2* x2 = (const uint2*)x8;   // 16 uint2 per 128 B u8 row
    const uint4* x4 = (const uint4*)xb;   // 16 uint4 per 256 B bf16 row

    // hoisted BN affine for this lane's 8 features
    float sc[8], sh[8];
    {
        const float4* s4 = (const float4*)(scale + fl * 8);
        const float4* h4 = (const float4*)(shift + fl * 8);
        float4 A = s4[0], B = s4[1], C = h4[0], E = h4[1];
        sc[0]=A.x; sc[1]=A.y; sc[2]=A.z; sc[3]=A.w; sc[4]=B.x; sc[5]=B.y; sc[6]=B.z; sc[7]=B.w;
        sh[0]=C.x; sh[1]=C.y; sh[2]=C.z; sh[3]=C.w; sh[4]=E.x; sh[5]=E.y; sh[6]=E.z; sh[7]=E.w;
    }

    // ---- Phase 1: gather + self + BN affine -> tile ----
    for (int r = 0; r < 16; ++r) {
        int row = (w << 4) + r;
        int node = base + row;
        if (node < N_NODES) {
            float a[8] = {0.f, 0.f, 0.f, 0.f, 0.f, 0.f, 0.f, 0.f};
            int e0 = poffs[node];
            int eE = poffs[node + 1];
            const int* ebase = csr + sub * 4;
            int4 ij = *(const int4*)(ebase + e0);          // this iter's 4 idx
            for (int e = e0; e < eE; e += 16) {
                int4 ijn = *(const int4*)(ebase + e + 16); // prefetch (slack-safe)
                if (IN_U8) {
                    float s0 = xsc[ij.x], s1 = xsc[ij.y], s2 = xsc[ij.z], s3 = xsc[ij.w];
                    uint2 q0 = x2[(size_t)ij.x * 16 + fl];
                    uint2 q1 = x2[(size_t)ij.y * 16 + fl];
                    uint2 q2 = x2[(size_t)ij.z * 16 + fl];
                    uint2 q3 = x2[(size_t)ij.w * 16 + fl];
                    acc8u(a, q0, s0); acc8u(a, q1, s1);
                    acc8u(a, q2, s2); acc8u(a, q3, s3);
                } else {
                    uint4 r0 = x4[(size_t)ij.x * 16 + fl];
                    uint4 r1 = x4[(size_t)ij.y * 16 + fl];
                    uint4 r2 = x4[(size_t)ij.z * 16 + fl];
                    uint4 r3 = x4[(size_t)ij.w * 16 + fl];
                    accbf(a, r0); accbf(a, r1); accbf(a, r2); accbf(a, r3);
                }
                ij = ijn;
            }
            // reduce across the 4 quarter-subs
#pragma unroll
            for (int j = 0; j < 8; ++j) a[j] += __shfl_xor(a[j], 32);
#pragma unroll
            for (int j = 0; j < 8; ++j) a[j] += __shfl_xor(a[j], 16);
            // self term with pad-overcount correction
            int dg = deg[node];
            float selfco = 1.f - (float)((eE - e0) - dg);
            if (IN_U8) {
                acc8u(a, x2[(size_t)node * 16 + fl], selfco * xsc[node]);
            } else {
                accbf_s(a, x4[(size_t)node * 16 + fl], selfco);
            }
            float cnt = (float)(dg + 1);
            if (lane < 16) {
                bf16x8 pk;
#pragma unroll
                for (int j = 0; j < 8; ++j)
                    pk[j] = (bf16_t)(a[j] * sc[j] + cnt * sh[j]);
                *(bf16x8*)(&tile[row * 136 + fl * 8]) = pk;
            }
        } else if (lane < 16) {
            bf16x8 z;
#pragma unroll
            for (int j = 0; j < 8; ++j) z[j] = (bf16_t)0.f;
            *(bf16x8*)(&tile[row * 136 + fl * 8]) = z;
        }
    }
    __syncthreads();

    // ---- Phase 2: GEMM1 + bias + relu -> tile (reused) ----
    const int q = lane >> 4;
    const int c16 = lane & 15;
    const int arow = (w << 4) + c16;

    bf16x8 afr[4];
#pragma unroll
    for (int ks = 0; ks < 4; ++ks)
        afr[ks] = *(const bf16x8*)(&tile[arow * 136 + ks * 32 + q * 8]);
    __syncthreads();

    f32x4 acc[8];
#pragma unroll
    for (int nt = 0; nt < 8; ++nt) acc[nt] = (f32x4){0.f, 0.f, 0.f, 0.f};
#pragma unroll
    for (int ks = 0; ks < 4; ++ks) {
#pragma unroll
        for (int nt = 0; nt < 8; ++nt) {
            bf16x8 bfr = *(const bf16x8*)(w1s + (((ks << 3) + nt) * 64 + lane) * 8);
            acc[nt] = __builtin_amdgcn_mfma_f32_16x16x32_bf16(afr[ks], bfr, acc[nt], 0, 0, 0);
        }
    }
#pragma unroll
    for (int nt = 0; nt < 8; ++nt) {
        float bias = b1[(nt << 4) + c16];
#pragma unroll
        for (int i = 0; i < 4; ++i) {
            float v = fmaxf(acc[nt][i] + bias, 0.f);
            int row = (w << 4) + (q << 2) + i;
            tile[row * 136 + (nt << 4) + c16] = (bf16_t)v;
        }
    }
    __syncthreads();

    // ---- Phase 3: GEMM2 + bias + relu + BN stats -> tile ----
    bf16x8 afr2[4];
#pragma unroll
    for (int ks = 0; ks < 4; ++ks)
        afr2[ks] = *(const bf16x8*)(&tile[arow * 136 + ks * 32 + q * 8]);
    __syncthreads(); // tile overwritten below

#pragma unroll
    for (int nt = 0; nt < 8; ++nt) acc[nt] = (f32x4){0.f, 0.f, 0.f, 0.f};
#pragma unroll
    for (int ks = 0; ks < 4; ++ks) {
#pragma unroll
        for (int nt = 0; nt < 8; ++nt) {
            bf16x8 bfr = *(const bf16x8*)(w2s + (((ks << 3) + nt) * 64 + lane) * 8);
            acc[nt] = __builtin_amdgcn_mfma_f32_16x16x32_bf16(afr2[ks], bfr, acc[nt], 0, 0, 0);
        }
    }
#pragma unroll
    for (int nt = 0; nt < 8; ++nt) {
        float bias = b2[(nt << 4) + c16];
        float s1 = 0.f, s2 = 0.f;
#pragma unroll
        for (int i = 0; i < 4; ++i) {
            float v = fmaxf(acc[nt][i] + bias, 0.f);
            int row = (w << 4) + (q << 2) + i;
            int node = base + row;
            if (node < N_NODES) {
                s1 += v;
                s2 += v * v;
            }
            tile[row * 136 + (nt << 4) + c16] = (bf16_t)v;
        }
        s1 += __shfl_down(s1, 32); s2 += __shfl_down(s2, 32);
        s1 += __shfl_down(s1, 16); s2 += __shfl_down(s2, 16);
        if (lane < 16) {
            atomicAdd(&stats[(nt << 4) + lane], s1);
            atomicAdd(&stats[DD + (nt << 4) + lane], s2);
        }
    }
    __syncthreads();

    // ---- Phase 4: quantize rows -> uint8 + scale. 4 threads per row. ----
    {
        int row4 = tid >> 2, t4 = tid & 3;
        int node = base + row4;
        if (node < N_NODES) {
            const bf16_t* tp = tile + row4 * 136 + t4 * 32;
            bf16x8 v0 = *(const bf16x8*)(tp);
            bf16x8 v1 = *(const bf16x8*)(tp + 8);
            bf16x8 v2 = *(const bf16x8*)(tp + 16);
            bf16x8 v3 = *(const bf16x8*)(tp + 24);
            float am = 0.f;
#pragma unroll
            for (int k = 0; k < 8; ++k) {
                am = fmaxf(am, (float)v0[k]);
                am = fmaxf(am, (float)v1[k]);
                am = fmaxf(am, (float)v2[k]);
                am = fmaxf(am, (float)v3[k]);
            }
            am = fmaxf(am, __shfl_xor(am, 1));
            am = fmaxf(am, __shfl_xor(am, 2));
            float inv = am > 0.f ? 255.f / am : 0.f;
            if (t4 == 0) ysc[node] = am * (1.f / 255.f);
            u32 u[8];
            u[0] = pack4u((float)v0[0], (float)v0[1], (float)v0[2], (float)v0[3], inv);
            u[1] = pack4u((float)v0[4], (float)v0[5], (float)v0[6], (float)v0[7], inv);
            u[2] = pack4u((float)v1[0], (float)v1[1], (float)v1[2], (float)v1[3], inv);
            u[3] = pack4u((float)v1[4], (float)v1[5], (float)v1[6], (float)v1[7], inv);
            u[4] = pack4u((float)v2[0], (float)v2[1], (float)v2[2], (float)v2[3], inv);
            u[5] = pack4u((float)v2[4], (float)v2[5], (float)v2[6], (float)v2[7], inv);
            u[6] = pack4u((float)v3[0], (float)v3[1], (float)v3[2], (float)v3[3], inv);
            u[7] = pack4u((float)v3[4], (float)v3[5], (float)v3[6], (float)v3[7], inv);
            uint4* yp = (uint4*)(y8 + (size_t)node * DD + t4 * 32);
            yp[0] = make_uint4(u[0], u[1], u[2], u[3]);
            yp[1] = make_uint4(u[4], u[5], u[6], u[7]);
        }
    }
}

// ---------------- pooling + head ----------------

// dequantizing segmented mean-pool over the u8 final-layer output
__global__ __launch_bounds__(128) void k_pool2u(
    const u8* __restrict__ y8, const float* __restrict__ ysc,
    const int* __restrict__ gstart,
    const float* __restrict__ scale, const float* __restrict__ shift,
    float* __restrict__ pooled)
{
    int g = blockIdx.x;
    int t = threadIdx.x;
    int s = gstart[g], e = gstart[g + 1];
    float acc = 0.f;
    for (int n = s; n < e; ++n)
        acc += ysc[n] * (float)y8[(size_t)n * DD + t];
    float cnt = (float)(e - s);
    float v = acc * scale[t] + cnt * shift[t];
    pooled[g * DD + t] = v / fmaxf(cnt, 1.0f);
}

__global__ void k_head(const float* __restrict__ pooled,
                       const float* __restrict__ lin1w, const float* __restrict__ lin1b,
                       const float* __restrict__ lin2w, const float* __restrict__ lin2b,
                       float* __restrict__ out) {
    __shared__ float p[DD];
    __shared__ float h[DD];
    int g = blockIdx.x;
    int t = threadIdx.x;
    p[t] = pooled[g * DD + t];
    __syncthreads();
    float a = lin1b[t];
    for (int k = 0; k < DD; ++k) a += p[k] * lin1w[k * DD + t];
    h[t] = fmaxf(a, 0.f);
    __syncthreads();
    if (t < 10) {
        float o = lin2b[t];
        for (int k = 0; k < DD; ++k) o += h[k] * lin2w[k * 10 + t];
        out[g * 10 + t] = o;
    }
}

// ---------------- launch ----------------

extern "C" void kernel_launch(void* const* d_in, const int* in_sizes, int n_in,
                              void* d_out, int out_size, void* d_ws, size_t ws_size,
                              hipStream_t stream) {
    const float* x      = (const float*)d_in[0];
    const int*   ei     = (const int*)d_in[1];
    const int*   batch  = (const int*)d_in[2];
    const float* W1s    = (const float*)d_in[3];
    const float* b1s    = (const float*)d_in[4];
    const float* W2s    = (const float*)d_in[5];
    const float* b2s    = (const float*)d_in[6];
    const float* gammas = (const float*)d_in[7];
    const float* betas  = (const float*)d_in[8];
    const float* lin1w  = (const float*)d_in[9];
    const float* lin1b  = (const float*)d_in[10];
    const float* lin2w  = (const float*)d_in[11];
    const float* lin2b  = (const float*)d_in[12];
    float* out = (float*)d_out;

    char* p = (char*)d_ws;
    size_t off = 0;
    auto alloc = [&](size_t bytes) -> char* {
        char* r = p + off;
        off += (bytes + 255) & ~(size_t)255;
        return r;
    };
    int*    deg    = (int*)alloc(N_NODES * 4);
    float*  stats  = (float*)alloc(3 * 256 * 4);
    size_t zero_bytes = off;
    int*    poffs  = (int*)alloc((N_NODES + 1) * 4);
    int*    cursor = (int*)alloc(N_NODES * 4);
    int*    csr    = (int*)alloc(((size_t)N_EDGES + 16 * N_NODES + 64) * 4); // pad-16 + prefetch slack
    bf16_t* xb     = (bf16_t*)alloc((size_t)N_NODES * DD * 2);  // bf16 input; q8b aliases it after L0
    u8*     q8a    = (u8*)alloc((size_t)N_NODES * DD);
    float*  sca    = (float*)alloc(N_NODES * 4);
    float*  scb    = (float*)alloc(N_NODES * 4);
    bf16_t* wshuf  = (bf16_t*)alloc(6 * 16384 * 2);
    float*  ss     = (float*)alloc(4 * 256 * 4);
    int*    gstart = (int*)alloc((N_GRAPHS + 1) * 4);
    float*  pooled = (float*)alloc(N_GRAPHS * DD * 4);
    if (off > ws_size) return;

    // q8b reuses xb's storage: xb is only read by L0; q8b is written by L1 and
    // read by L2 (stream-ordered on one stream, no overlap).
    u8* q8b = (u8*)xb;

    const int* srcA = ei;
    const int* dstA = ei + N_EDGES;

    k_zero<<<256, 256, 0, stream>>>((float4*)d_ws, (int)(zero_bytes / 16));
    k_hist<<<1024, 256, 0, stream>>>(dstA, deg);
    k_scan<<<1, 1024, 0, stream>>>(deg, poffs, cursor);
    k_fill<<<1024, 256, 0, stream>>>(srcA, dstA, cursor, csr);
    k_pad<<<(N_NODES * 16 + 255) / 256, 256, 0, stream>>>(deg, poffs, csr);
    k_cvt<<<1024, 256, 0, stream>>>(x, xb);
    k_shufw<<<(6 * 16384 + 255) / 256, 256, 0, stream>>>(W1s, W2s, wshuf);
    k_aff_init<<<1, 128, 0, stream>>>(ss);
    k_gbounds<<<(N_NODES + 255) / 256, 256, 0, stream>>>(batch, gstart);

    // L0: xb (bf16) -> q8a. L1: q8a -> q8b (aliases xb). L2: q8b -> q8a.
    k_layer<false><<<NTILES, 256, 0, stream>>>(
        xb, q8a, sca, q8a, sca, poffs, csr, deg,
        ss + 0 * 256, ss + 0 * 256 + 128,
        wshuf + 0 * 16384, wshuf + 1 * 16384,
        b1s + 0 * DD, b2s + 0 * DD, stats + 0 * 256);
    k_aff_update<<<1, 128, 0, stream>>>(stats + 0 * 256, gammas + 0 * DD, betas + 0 * DD,
                                        ss + 1 * 256, ss + 1 * 256 + 128);
    k_layer<true><<<NTILES, 256, 0, stream>>>(
        xb, q8a, sca, q8b, scb, poffs, csr, deg,
        ss + 1 * 256, ss + 1 * 256 + 128,
        wshuf + 2 * 16384, wshuf + 3 * 16384,
        b1s + 1 * DD, b2s + 1 * DD, stats + 1 * 256);
    k_aff_update<<<1, 128, 0, stream>>>(stats + 1 * 256, gammas + 1 * DD, betas + 1 * DD,
                                        ss + 2 * 256, ss + 2 * 256 + 128);
    k_layer<true><<<NTILES, 256, 0, stream>>>(
        xb, q8b, scb, q8a, sca, poffs, csr, deg,
        ss + 2 * 256, ss + 2 * 256 + 128,
        wshuf + 4 * 16384, wshuf + 5 * 16384,
        b1s + 2 * DD, b2s + 2 * DD, stats + 2 * 256);
    k_aff_update<<<1, 128, 0, stream>>>(stats + 2 * 256, gammas + 2 * DD, betas + 2 * DD,
                                        ss + 3 * 256, ss + 3 * 256 + 128);

    k_pool2u<<<N_GRAPHS, 128, 0, stream>>>(q8a, sca, gstart,
                                           ss + 3 * 256, ss + 3 * 256 + 128, pooled);
    k_head<<<N_GRAPHS, 128, 0, stream>>>(pooled, lin1w, lin1b, lin2w, lin2b, out);
}

// Round 10
// 1191.278 us; speedup vs baseline: 1.0862x; 1.0862x over previous
//
#include <hip/hip_runtime.h>
#include <hip/hip_bf16.h>

#define N_NODES 100000
#define N_EDGES 1600000
#define DD 128
#define N_GRAPHS 512
#define BN_EPS 1e-5f
#define NTILES 1563            // ceil(100000/64)

typedef unsigned int u32;
typedef unsigned char u8;
typedef __bf16 bf16_t;
typedef __bf16 bf16x2 __attribute__((ext_vector_type(2)));
typedef __bf16 bf16x4 __attribute__((ext_vector_type(4)));
typedef __bf16 bf16x8 __attribute__((ext_vector_type(8)));
typedef float f32x4 __attribute__((ext_vector_type(4)));

__device__ __forceinline__ float bflo2f(u32 u) {
    union { u32 i; float f; } x; x.i = u << 16; return x.f;
}
__device__ __forceinline__ float bfhi2f(u32 u) {
    union { u32 i; float f; } x; x.i = u & 0xffff0000u; return x.f;
}
__device__ __forceinline__ u32 pack4u(float v0, float v1, float v2, float v3, float inv) {
    u32 q0 = (u32)fminf(rintf(v0 * inv), 255.f);
    u32 q1 = (u32)fminf(rintf(v1 * inv), 255.f);
    u32 q2 = (u32)fminf(rintf(v2 * inv), 255.f);
    u32 q3 = (u32)fminf(rintf(v3 * inv), 255.f);
    return q0 | (q1 << 8) | (q2 << 16) | (q3 << 24);
}

// ---------------- utility kernels ----------------

__global__ void k_zero(float4* p, int n) {
    float4 z = make_float4(0.f, 0.f, 0.f, 0.f);
    for (int i = blockIdx.x * blockDim.x + threadIdx.x; i < n; i += gridDim.x * blockDim.x)
        p[i] = z;
}

__global__ void k_hist(const int* __restrict__ dst, int* __restrict__ deg) {
    for (int e = blockIdx.x * blockDim.x + threadIdx.x; e < N_EDGES; e += gridDim.x * blockDim.x)
        atomicAdd(&deg[dst[e]], 1);
}

// single block: exclusive scan of padded degrees ((deg+3)&~3) -> poffs, cursor
__global__ void k_scan(const int* __restrict__ deg, int* __restrict__ poffs, int* __restrict__ cursor) {
    __shared__ int ps[1024];
    int t = threadIdx.x;
    int s = 0;
    if (t < 1000) {
        const int4* d4 = (const int4*)(deg + t * 100);
        for (int i = 0; i < 25; ++i) {
            int4 v = d4[i];
            s += ((v.x + 3) & ~3) + ((v.y + 3) & ~3) + ((v.z + 3) & ~3) + ((v.w + 3) & ~3);
        }
    }
    ps[t] = s;
    __syncthreads();
    for (int d2 = 1; d2 < 1024; d2 <<= 1) {
        int v = (t >= d2) ? ps[t - d2] : 0;
        __syncthreads();
        ps[t] += v;
        __syncthreads();
    }
    int run = ps[t] - s;
    if (t < 1000) {
        for (int i = 0; i < 100; ++i) {
            int idx = t * 100 + i;
            poffs[idx] = run; cursor[idx] = run;
            run += (deg[idx] + 3) & ~3;
        }
    }
    if (t == 1023) poffs[N_NODES] = ps[1023];
}

__global__ void k_fill(const int* __restrict__ src, const int* __restrict__ dst,
                       int* __restrict__ cursor, int* __restrict__ csr) {
    for (int e = blockIdx.x * blockDim.x + threadIdx.x; e < N_EDGES; e += gridDim.x * blockDim.x) {
        int pos = atomicAdd(&cursor[dst[e]], 1);
        csr[pos] = src[e];
    }
}

// fill pad slots with the DEST node's own index; gather subtracts the
// overcount via the self-term coefficient (1 - #pads). Self line is L1-hot.
__global__ void k_pad(const int* __restrict__ deg, const int* __restrict__ poffs,
                      int* __restrict__ csr) {
    int t = blockIdx.x * blockDim.x + threadIdx.x;
    if (t >= N_NODES * 4) return;
    int n = t >> 2, j = t & 3;
    int s = poffs[n] + deg[n];
    if (s + j < poffs[n + 1]) csr[s + j] = n;
}

__global__ void k_cvt(const float* __restrict__ x, bf16_t* __restrict__ xb) {
    const int n4 = N_NODES * DD / 4;
    const float4* x4 = (const float4*)x;
    bf16x4* o4 = (bf16x4*)xb;
    for (int i = blockIdx.x * blockDim.x + threadIdx.x; i < n4; i += gridDim.x * blockDim.x) {
        float4 v = x4[i];
        bf16x4 o;
        o.x = (bf16_t)v.x; o.y = (bf16_t)v.y; o.z = (bf16_t)v.z; o.w = (bf16_t)v.w;
        o4[i] = o;
    }
}

// Pre-shuffle the 6 weight matrices into exact MFMA B-fragment order (bf16).
__global__ void k_shufw(const float* __restrict__ W1s, const float* __restrict__ W2s,
                        bf16_t* __restrict__ wshuf) {
    int t = blockIdx.x * blockDim.x + threadIdx.x;
    if (t >= 6 * 16384) return;
    int g  = t >> 14;
    int r  = t & 16383;
    int j  = r & 7;
    int L  = (r >> 3) & 63;
    int nt = (r >> 9) & 7;
    int ks = r >> 12;
    int l  = g >> 1;
    const float* src = (g & 1) ? (W2s + l * 16384) : (W1s + l * 16384);
    int k = ks * 32 + (L >> 4) * 8 + j;
    int n = nt * 16 + (L & 15);
    wshuf[t] = (bf16_t)src[k * DD + n];
}

__global__ void k_aff_init(float* __restrict__ ss) {
    int f = threadIdx.x;
    if (f < DD) { ss[f] = 1.0f; ss[DD + f] = 0.0f; }
}

__global__ void k_aff_update(const float* __restrict__ stats, const float* __restrict__ gamma,
                             const float* __restrict__ beta, float* __restrict__ scale,
                             float* __restrict__ shift) {
    int f = threadIdx.x;
    if (f < DD) {
        float mu  = stats[f] * (1.0f / N_NODES);
        float var = stats[DD + f] * (1.0f / N_NODES) - mu * mu;
        float inv = rsqrtf(var + BN_EPS);
        float sc  = gamma[f] * inv;
        scale[f] = sc;
        shift[f] = beta[f] - mu * sc;
    }
}

__global__ void k_gbounds(const int* __restrict__ batch, int* __restrict__ gstart) {
    int i = blockIdx.x * blockDim.x + threadIdx.x;
    if (i >= N_NODES) return;
    int b = batch[i];
    int bp = (i == 0) ? -1 : batch[i - 1];
    for (int g = bp + 1; g <= b; ++g) gstart[g] = i;
    if (i == N_NODES - 1)
        for (int g = b + 1; g <= N_GRAPHS; ++g) gstart[g] = N_NODES;
}

// ---------------- fused GIN layer ----------------
// block = 256 (4 waves), 64 nodes. Gather redesign (divergence-free): lane l
// covers features (2l, 2l+1). One edge = ONE wave-load covering the row at
// 2 B/lane (u8, 1 line) or 4 B/lane (bf16, 2 lines). Edge indices + row
// scales are wave-uniform (readfirstlane -> s_load + saddr vector loads).
// No cross-lane reduction. Pads (x4) point at the node itself; self term
// uses coefficient (1 - #pads). Output always uint8 + per-row scale.
template<bool IN_U8>
__global__ __launch_bounds__(256, 8) void k_layer(
    const bf16_t* __restrict__ xb,
    const u8* __restrict__ x8, const float* __restrict__ xsc,
    u8* __restrict__ y8, float* __restrict__ ysc,
    const int* __restrict__ poffs, const int* __restrict__ csr,
    const int* __restrict__ deg,
    const float* __restrict__ scale, const float* __restrict__ shift,
    const bf16_t* __restrict__ w1s, const bf16_t* __restrict__ w2s,
    const float* __restrict__ b1, const float* __restrict__ b2,
    float* __restrict__ stats)
{
    __shared__ __align__(16) bf16_t tile[64 * 136];

    const int tid  = threadIdx.x;
    const int w    = tid >> 6;
    const int lane = tid & 63;
    const int base = blockIdx.x * 64;
    const int fb   = lane << 1;          // this lane's feature pair

    const float sc0 = scale[fb], sc1 = scale[fb + 1];
    const float sh0 = shift[fb], sh1 = shift[fb + 1];

    // ---- Phase 1: divergence-free per-edge gather -> tile ----
    for (int r = 0; r < 16; ++r) {
        int row = (w << 4) + r;
        int node = base + row;
        if (node < N_NODES) {
            float a0 = 0.f, a1 = 0.f;
            int e0 = poffs[node];
            int eE = poffs[node + 1];
            // current group's indices (wave-uniform scalars)
            int4 qv = *(const int4*)(csr + e0);
            int i0 = __builtin_amdgcn_readfirstlane(qv.x);
            int i1 = __builtin_amdgcn_readfirstlane(qv.y);
            int i2 = __builtin_amdgcn_readfirstlane(qv.z);
            int i3 = __builtin_amdgcn_readfirstlane(qv.w);
            for (int e = e0; e < eE; e += 4) {
                int4 qn = *(const int4*)(csr + e + 4);   // slack-safe prefetch
                if (IN_U8) {
                    float s0 = xsc[i0], s1 = xsc[i1], s2 = xsc[i2], s3 = xsc[i3];
                    u32 v0 = *(const unsigned short*)(x8 + ((size_t)i0 << 7) + fb);
                    u32 v1 = *(const unsigned short*)(x8 + ((size_t)i1 << 7) + fb);
                    u32 v2 = *(const unsigned short*)(x8 + ((size_t)i2 << 7) + fb);
                    u32 v3 = *(const unsigned short*)(x8 + ((size_t)i3 << 7) + fb);
                    a0 += s0 * (float)(v0 & 0xffu); a1 += s0 * (float)(v0 >> 8);
                    a0 += s1 * (float)(v1 & 0xffu); a1 += s1 * (float)(v1 >> 8);
                    a0 += s2 * (float)(v2 & 0xffu); a1 += s2 * (float)(v2 >> 8);
                    a0 += s3 * (float)(v3 & 0xffu); a1 += s3 * (float)(v3 >> 8);
                } else {
                    u32 v0 = *(const u32*)((const u8*)xb + ((size_t)i0 << 8) + (fb << 1));
                    u32 v1 = *(const u32*)((const u8*)xb + ((size_t)i1 << 8) + (fb << 1));
                    u32 v2 = *(const u32*)((const u8*)xb + ((size_t)i2 << 8) + (fb << 1));
                    u32 v3 = *(const u32*)((const u8*)xb + ((size_t)i3 << 8) + (fb << 1));
                    a0 += bflo2f(v0) + bflo2f(v1) + bflo2f(v2) + bflo2f(v3);
                    a1 += bfhi2f(v0) + bfhi2f(v1) + bfhi2f(v2) + bfhi2f(v3);
                }
                i0 = __builtin_amdgcn_readfirstlane(qn.x);
                i1 = __builtin_amdgcn_readfirstlane(qn.y);
                i2 = __builtin_amdgcn_readfirstlane(qn.z);
                i3 = __builtin_amdgcn_readfirstlane(qn.w);
            }
            // self term with pad-overcount correction
            int dg = deg[node];
            float selfco = 1.f - (float)((eE - e0) - dg);
            if (IN_U8) {
                u32 sv = *(const unsigned short*)(x8 + ((size_t)node << 7) + fb);
                float ss = selfco * xsc[node];
                a0 += ss * (float)(sv & 0xffu); a1 += ss * (float)(sv >> 8);
            } else {
                u32 sv = *(const u32*)((const u8*)xb + ((size_t)node << 8) + (fb << 1));
                a0 += selfco * bflo2f(sv); a1 += selfco * bfhi2f(sv);
            }
            float cnt = (float)(dg + 1);
            bf16x2 pk;
            pk.x = (bf16_t)(a0 * sc0 + cnt * sh0);
            pk.y = (bf16_t)(a1 * sc1 + cnt * sh1);
            *(bf16x2*)(&tile[row * 136 + fb]) = pk;
        } else {
            bf16x2 z; z.x = (bf16_t)0.f; z.y = (bf16_t)0.f;
            *(bf16x2*)(&tile[row * 136 + fb]) = z;
        }
    }
    __syncthreads();

    // ---- Phase 2: GEMM1 + bias + relu -> tile (reused) ----
    const int q = lane >> 4;
    const int c16 = lane & 15;
    const int arow = (w << 4) + c16;

    bf16x8 afr[4];
#pragma unroll
    for (int ks = 0; ks < 4; ++ks)
        afr[ks] = *(const bf16x8*)(&tile[arow * 136 + ks * 32 + q * 8]);
    __syncthreads();

    f32x4 acc[8];
#pragma unroll
    for (int nt = 0; nt < 8; ++nt) acc[nt] = (f32x4){0.f, 0.f, 0.f, 0.f};
#pragma unroll
    for (int ks = 0; ks < 4; ++ks) {
#pragma unroll
        for (int nt = 0; nt < 8; ++nt) {
            bf16x8 bfr = *(const bf16x8*)(w1s + (((ks << 3) + nt) * 64 + lane) * 8);
            acc[nt] = __builtin_amdgcn_mfma_f32_16x16x32_bf16(afr[ks], bfr, acc[nt], 0, 0, 0);
        }
    }
#pragma unroll
    for (int nt = 0; nt < 8; ++nt) {
        float bias = b1[(nt << 4) + c16];
#pragma unroll
        for (int i = 0; i < 4; ++i) {
            float v = fmaxf(acc[nt][i] + bias, 0.f);
            int row = (w << 4) + (q << 2) + i;
            tile[row * 136 + (nt << 4) + c16] = (bf16_t)v;
        }
    }
    __syncthreads();

    // ---- Phase 3: GEMM2 + bias + relu + BN stats -> tile ----
    bf16x8 afr2[4];
#pragma unroll
    for (int ks = 0; ks < 4; ++ks)
        afr2[ks] = *(const bf16x8*)(&tile[arow * 136 + ks * 32 + q * 8]);
    __syncthreads(); // tile overwritten below

#pragma unroll
    for (int nt = 0; nt < 8; ++nt) acc[nt] = (f32x4){0.f, 0.f, 0.f, 0.f};
#pragma unroll
    for (int ks = 0; ks < 4; ++ks) {
#pragma unroll
        for (int nt = 0; nt < 8; ++nt) {
            bf16x8 bfr = *(const bf16x8*)(w2s + (((ks << 3) + nt) * 64 + lane) * 8);
            acc[nt] = __builtin_amdgcn_mfma_f32_16x16x32_bf16(afr2[ks], bfr, acc[nt], 0, 0, 0);
        }
    }
#pragma unroll
    for (int nt = 0; nt < 8; ++nt) {
        float bias = b2[(nt << 4) + c16];
        float s1 = 0.f, s2 = 0.f;
#pragma unroll
        for (int i = 0; i < 4; ++i) {
            float v = fmaxf(acc[nt][i] + bias, 0.f);
            int row = (w << 4) + (q << 2) + i;
            int node = base + row;
            if (node < N_NODES) {
                s1 += v;
                s2 += v * v;
            }
            tile[row * 136 + (nt << 4) + c16] = (bf16_t)v;
        }
        s1 += __shfl_down(s1, 32); s2 += __shfl_down(s2, 32);
        s1 += __shfl_down(s1, 16); s2 += __shfl_down(s2, 16);
        if (lane < 16) {
            atomicAdd(&stats[(nt << 4) + lane], s1);
            atomicAdd(&stats[DD + (nt << 4) + lane], s2);
        }
    }
    __syncthreads();

    // ---- Phase 4: quantize rows -> uint8 + scale. 4 threads per row. ----
    {
        int row4 = tid >> 2, t4 = tid & 3;
        int node = base + row4;
        if (node < N_NODES) {
            const bf16_t* tp = tile + row4 * 136 + t4 * 32;
            bf16x8 v0 = *(const bf16x8*)(tp);
            bf16x8 v1 = *(const bf16x8*)(tp + 8);
            bf16x8 v2 = *(const bf16x8*)(tp + 16);
            bf16x8 v3 = *(const bf16x8*)(tp + 24);
            float am = 0.f;
#pragma unroll
            for (int k = 0; k < 8; ++k) {
                am = fmaxf(am, (float)v0[k]);
                am = fmaxf(am, (float)v1[k]);
                am = fmaxf(am, (float)v2[k]);
                am = fmaxf(am, (float)v3[k]);
            }
            am = fmaxf(am, __shfl_xor(am, 1));
            am = fmaxf(am, __shfl_xor(am, 2));
            float inv = am > 0.f ? 255.f / am : 0.f;
            if (t4 == 0) ysc[node] = am * (1.f / 255.f);
            u32 u[8];
            u[0] = pack4u((float)v0[0], (float)v0[1], (float)v0[2], (float)v0[3], inv);
            u[1] = pack4u((float)v0[4], (float)v0[5], (float)v0[6], (float)v0[7], inv);
            u[2] = pack4u((float)v1[0], (float)v1[1], (float)v1[2], (float)v1[3], inv);
            u[3] = pack4u((float)v1[4], (float)v1[5], (float)v1[6], (float)v1[7], inv);
            u[4] = pack4u((float)v2[0], (float)v2[1], (float)v2[2], (float)v2[3], inv);
            u[5] = pack4u((float)v2[4], (float)v2[5], (float)v2[6], (float)v2[7], inv);
            u[6] = pack4u((float)v3[0], (float)v3[1], (float)v3[2], (float)v3[3], inv);
            u[7] = pack4u((float)v3[4], (float)v3[5], (float)v3[6], (float)v3[7], inv);
            uint4* yp = (uint4*)(y8 + (size_t)node * DD + t4 * 32);
            yp[0] = make_uint4(u[0], u[1], u[2], u[3]);
            yp[1] = make_uint4(u[4], u[5], u[6], u[7]);
        }
    }
}

// ---------------- pooling + head ----------------

// dequantizing segmented mean-pool over the u8 final-layer output
__global__ __launch_bounds__(128) void k_pool2u(
    const u8* __restrict__ y8, const float* __restrict__ ysc,
    const int* __restrict__ gstart,
    const float* __restrict__ scale, const float* __restrict__ shift,
    float* __restrict__ pooled)
{
    int g = blockIdx.x;
    int t = threadIdx.x;
    int s = gstart[g], e = gstart[g + 1];
    float acc = 0.f;
    for (int n = s; n < e; ++n)
        acc += ysc[n] * (float)y8[(size_t)n * DD + t];
    float cnt = (float)(e - s);
    float v = acc * scale[t] + cnt * shift[t];
    pooled[g * DD + t] = v / fmaxf(cnt, 1.0f);
}

__global__ void k_head(const float* __restrict__ pooled,
                       const float* __restrict__ lin1w, const float* __restrict__ lin1b,
                       const float* __restrict__ lin2w, const float* __restrict__ lin2b,
                       float* __restrict__ out) {
    __shared__ float p[DD];
    __shared__ float h[DD];
    int g = blockIdx.x;
    int t = threadIdx.x;
    p[t] = pooled[g * DD + t];
    __syncthreads();
    float a = lin1b[t];
    for (int k = 0; k < DD; ++k) a += p[k] * lin1w[k * DD + t];
    h[t] = fmaxf(a, 0.f);
    __syncthreads();
    if (t < 10) {
        float o = lin2b[t];
        for (int k = 0; k < DD; ++k) o += h[k] * lin2w[k * 10 + t];
        out[g * 10 + t] = o;
    }
}

// ---------------- launch ----------------

extern "C" void kernel_launch(void* const* d_in, const int* in_sizes, int n_in,
                              void* d_out, int out_size, void* d_ws, size_t ws_size,
                              hipStream_t stream) {
    const float* x      = (const float*)d_in[0];
    const int*   ei     = (const int*)d_in[1];
    const int*   batch  = (const int*)d_in[2];
    const float* W1s    = (const float*)d_in[3];
    const float* b1s    = (const float*)d_in[4];
    const float* W2s    = (const float*)d_in[5];
    const float* b2s    = (const float*)d_in[6];
    const float* gammas = (const float*)d_in[7];
    const float* betas  = (const float*)d_in[8];
    const float* lin1w  = (const float*)d_in[9];
    const float* lin1b  = (const float*)d_in[10];
    const float* lin2w  = (const float*)d_in[11];
    const float* lin2b  = (const float*)d_in[12];
    float* out = (float*)d_out;

    char* p = (char*)d_ws;
    size_t off = 0;
    auto alloc = [&](size_t bytes) -> char* {
        char* r = p + off;
        off += (bytes + 255) & ~(size_t)255;
        return r;
    };
    int*    deg    = (int*)alloc(N_NODES * 4);
    float*  stats  = (float*)alloc(3 * 256 * 4);
    size_t zero_bytes = off;
    int*    poffs  = (int*)alloc((N_NODES + 1) * 4);
    int*    cursor = (int*)alloc(N_NODES * 4);
    int*    csr    = (int*)alloc(((size_t)N_EDGES + 4 * N_NODES + 64) * 4); // pad-4 + prefetch slack
    bf16_t* xb     = (bf16_t*)alloc((size_t)N_NODES * DD * 2);  // bf16 input; q8b aliases it after L0
    u8*     q8a    = (u8*)alloc((size_t)N_NODES * DD);
    float*  sca    = (float*)alloc(N_NODES * 4);
    float*  scb    = (float*)alloc(N_NODES * 4);
    bf16_t* wshuf  = (bf16_t*)alloc(6 * 16384 * 2);
    float*  ss     = (float*)alloc(4 * 256 * 4);
    int*    gstart = (int*)alloc((N_GRAPHS + 1) * 4);
    float*  pooled = (float*)alloc(N_GRAPHS * DD * 4);
    if (off > ws_size) return;

    // q8b reuses xb's storage: xb is only read by L0; q8b is written by L1 and
    // read by L2 (stream-ordered on one stream, no overlap).
    u8* q8b = (u8*)xb;

    const int* srcA = ei;
    const int* dstA = ei + N_EDGES;

    k_zero<<<256, 256, 0, stream>>>((float4*)d_ws, (int)(zero_bytes / 16));
    k_hist<<<1024, 256, 0, stream>>>(dstA, deg);
    k_scan<<<1, 1024, 0, stream>>>(deg, poffs, cursor);
    k_fill<<<1024, 256, 0, stream>>>(srcA, dstA, cursor, csr);
    k_pad<<<(N_NODES * 4 + 255) / 256, 256, 0, stream>>>(deg, poffs, csr);
    k_cvt<<<1024, 256, 0, stream>>>(x, xb);
    k_shufw<<<(6 * 16384 + 255) / 256, 256, 0, stream>>>(W1s, W2s, wshuf);
    k_aff_init<<<1, 128, 0, stream>>>(ss);
    k_gbounds<<<(N_NODES + 255) / 256, 256, 0, stream>>>(batch, gstart);

    // L0: xb (bf16) -> q8a. L1: q8a -> q8b (aliases xb). L2: q8b -> q8a.
    k_layer<false><<<NTILES, 256, 0, stream>>>(
        xb, q8a, sca, q8a, sca, poffs, csr, deg,
        ss + 0 * 256, ss + 0 * 256 + 128,
        wshuf + 0 * 16384, wshuf + 1 * 16384,
        b1s + 0 * DD, b2s + 0 * DD, stats + 0 * 256);
    k_aff_update<<<1, 128, 0, stream>>>(stats + 0 * 256, gammas + 0 * DD, betas + 0 * DD,
                                        ss + 1 * 256, ss + 1 * 256 + 128);
    k_layer<true><<<NTILES, 256, 0, stream>>>(
        xb, q8a, sca, q8b, scb, poffs, csr, deg,
        ss + 1 * 256, ss + 1 * 256 + 128,
        wshuf + 2 * 16384, wshuf + 3 * 16384,
        b1s + 1 * DD, b2s + 1 * DD, stats + 1 * 256);
    k_aff_update<<<1, 128, 0, stream>>>(stats + 1 * 256, gammas + 1 * DD, betas + 1 * DD,
                                        ss + 2 * 256, ss + 2 * 256 + 128);
    k_layer<true><<<NTILES, 256, 0, stream>>>(
        xb, q8b, scb, q8a, sca, poffs, csr, deg,
        ss + 2 * 256, ss + 2 * 256 + 128,
        wshuf + 4 * 16384, wshuf + 5 * 16384,
        b1s + 2 * DD, b2s + 2 * DD, stats + 2 * 256);
    k_aff_update<<<1, 128, 0, stream>>>(stats + 2 * 256, gammas + 2 * DD, betas + 2 * DD,
                                        ss + 3 * 256, ss + 3 * 256 + 128);

    k_pool2u<<<N_GRAPHS, 128, 0, stream>>>(q8a, sca, gstart,
                                           ss + 3 * 256, ss + 3 * 256 + 128, pooled);
    k_head<<<N_GRAPHS, 128, 0, stream>>>(pooled, lin1w, lin1b, lin2w, lin2b, out);
}

// Round 11
// 1125.714 us; speedup vs baseline: 1.1494x; 1.0582x over previous
//
#include <hip/hip_runtime.h>
#include <hip/hip_bf16.h>

#define N_NODES 100000
#define N_EDGES 1600000
#define DD 128
#define N_GRAPHS 512
#define BN_EPS 1e-5f
#define NTILES 1563            // ceil(100000/64)
#define SCAN_B 98              // ceil(100000/1024)

typedef unsigned int u32;
typedef unsigned char u8;
typedef __bf16 bf16_t;
typedef __bf16 bf16x2 __attribute__((ext_vector_type(2)));
typedef __bf16 bf16x4 __attribute__((ext_vector_type(4)));
typedef __bf16 bf16x8 __attribute__((ext_vector_type(8)));
typedef float f32x4 __attribute__((ext_vector_type(4)));

__device__ __forceinline__ float bflo2f(u32 u) {
    union { u32 i; float f; } x; x.i = u << 16; return x.f;
}
__device__ __forceinline__ float bfhi2f(u32 u) {
    union { u32 i; float f; } x; x.i = u & 0xffff0000u; return x.f;
}
__device__ __forceinline__ u32 pack4u(float v0, float v1, float v2, float v3, float inv) {
    u32 q0 = (u32)fminf(rintf(v0 * inv), 255.f);
    u32 q1 = (u32)fminf(rintf(v1 * inv), 255.f);
    u32 q2 = (u32)fminf(rintf(v2 * inv), 255.f);
    u32 q3 = (u32)fminf(rintf(v3 * inv), 255.f);
    return q0 | (q1 << 8) | (q2 << 16) | (q3 << 24);
}

// ---------------- utility kernels ----------------

__global__ void k_zero(float4* p, int n) {
    float4 z = make_float4(0.f, 0.f, 0.f, 0.f);
    for (int i = blockIdx.x * blockDim.x + threadIdx.x; i < n; i += gridDim.x * blockDim.x)
        p[i] = z;
}

__global__ void k_hist(const int* __restrict__ dst, int* __restrict__ deg) {
    for (int e = blockIdx.x * blockDim.x + threadIdx.x; e < N_EDGES; e += gridDim.x * blockDim.x)
        atomicAdd(&deg[dst[e]], 1);
}

// hierarchical scan of padded degrees ((deg+3)&~3) -> poffs, cursor
__global__ void k_scan1(const int* __restrict__ deg, int* __restrict__ bsum) {
    __shared__ int sh[1024];
    int b = blockIdx.x, t = threadIdx.x;
    int i = b * 1024 + t;
    int pd = (i < N_NODES) ? ((deg[i] + 3) & ~3) : 0;
    sh[t] = pd;
    __syncthreads();
    for (int s = 512; s > 0; s >>= 1) {
        if (t < s) sh[t] += sh[t + s];
        __syncthreads();
    }
    if (t == 0) bsum[b] = sh[0];
}
__global__ void k_scan2(const int* __restrict__ bsum, int* __restrict__ bbase,
                        int* __restrict__ poffs) {
    __shared__ int sh[128];
    int t = threadIdx.x;
    int v = (t < SCAN_B) ? bsum[t] : 0;
    sh[t] = v;
    __syncthreads();
    for (int d = 1; d < 128; d <<= 1) {
        int o = (t >= d) ? sh[t - d] : 0;
        __syncthreads();
        sh[t] += o;
        __syncthreads();
    }
    if (t < SCAN_B) bbase[t] = sh[t] - v;          // exclusive base per block
    if (t == SCAN_B - 1) poffs[N_NODES] = sh[t];   // total padded edges
}
__global__ void k_scan3(const int* __restrict__ deg, const int* __restrict__ bbase,
                        int* __restrict__ poffs, int* __restrict__ cursor) {
    __shared__ int sh[1024];
    int b = blockIdx.x, t = threadIdx.x;
    int i = b * 1024 + t;
    int pd = (i < N_NODES) ? ((deg[i] + 3) & ~3) : 0;
    sh[t] = pd;
    __syncthreads();
    for (int d = 1; d < 1024; d <<= 1) {
        int o = (t >= d) ? sh[t - d] : 0;
        __syncthreads();
        sh[t] += o;
        __syncthreads();
    }
    if (i < N_NODES) {
        int off = bbase[b] + sh[t] - pd;
        poffs[i] = off; cursor[i] = off;
    }
}

__global__ void k_fill(const int* __restrict__ src, const int* __restrict__ dst,
                       int* __restrict__ cursor, int* __restrict__ csr) {
    for (int e = blockIdx.x * blockDim.x + threadIdx.x; e < N_EDGES; e += gridDim.x * blockDim.x) {
        int pos = atomicAdd(&cursor[dst[e]], 1);
        csr[pos] = src[e];
    }
}

// fill pad slots with the DEST node's own index; gather subtracts the
// overcount via the self-term coefficient (1 - #pads). Self line is L1-hot.
__global__ void k_pad(const int* __restrict__ deg, const int* __restrict__ poffs,
                      int* __restrict__ csr) {
    int t = blockIdx.x * blockDim.x + threadIdx.x;
    if (t >= N_NODES * 4) return;
    int n = t >> 2, j = t & 3;
    int s = poffs[n] + deg[n];
    if (s + j < poffs[n + 1]) csr[s + j] = n;
}

__global__ void k_cvt(const float* __restrict__ x, bf16_t* __restrict__ xb) {
    const int n4 = N_NODES * DD / 4;
    const float4* x4 = (const float4*)x;
    bf16x4* o4 = (bf16x4*)xb;
    for (int i = blockIdx.x * blockDim.x + threadIdx.x; i < n4; i += gridDim.x * blockDim.x) {
        float4 v = x4[i];
        bf16x4 o;
        o.x = (bf16_t)v.x; o.y = (bf16_t)v.y; o.z = (bf16_t)v.z; o.w = (bf16_t)v.w;
        o4[i] = o;
    }
}

// Pre-shuffle the 6 weight matrices into exact MFMA B-fragment order (bf16).
__global__ void k_shufw(const float* __restrict__ W1s, const float* __restrict__ W2s,
                        bf16_t* __restrict__ wshuf) {
    int t = blockIdx.x * blockDim.x + threadIdx.x;
    if (t >= 6 * 16384) return;
    int g  = t >> 14;
    int r  = t & 16383;
    int j  = r & 7;
    int L  = (r >> 3) & 63;
    int nt = (r >> 9) & 7;
    int ks = r >> 12;
    int l  = g >> 1;
    const float* src = (g & 1) ? (W2s + l * 16384) : (W1s + l * 16384);
    int k = ks * 32 + (L >> 4) * 8 + j;
    int n = nt * 16 + (L & 15);
    wshuf[t] = (bf16_t)src[k * DD + n];
}

__global__ void k_aff_init(float* __restrict__ ss) {
    int f = threadIdx.x;
    if (f < DD) { ss[f] = 1.0f; ss[DD + f] = 0.0f; }
}

__global__ void k_aff_update(const float* __restrict__ stats, const float* __restrict__ gamma,
                             const float* __restrict__ beta, float* __restrict__ scale,
                             float* __restrict__ shift) {
    int f = threadIdx.x;
    if (f < DD) {
        float mu  = stats[f] * (1.0f / N_NODES);
        float var = stats[DD + f] * (1.0f / N_NODES) - mu * mu;
        float inv = rsqrtf(var + BN_EPS);
        float sc  = gamma[f] * inv;
        scale[f] = sc;
        shift[f] = beta[f] - mu * sc;
    }
}

__global__ void k_gbounds(const int* __restrict__ batch, int* __restrict__ gstart) {
    int i = blockIdx.x * blockDim.x + threadIdx.x;
    if (i >= N_NODES) return;
    int b = batch[i];
    int bp = (i == 0) ? -1 : batch[i - 1];
    for (int g = bp + 1; g <= b; ++g) gstart[g] = i;
    if (i == N_NODES - 1)
        for (int g = b + 1; g <= N_GRAPHS; ++g) gstart[g] = N_NODES;
}

// ---------------- fused GIN layer ----------------
// block = 256 (4 waves), 64 nodes. Divergence-free gather: lane l covers
// features (2l, 2l+1); one edge = one wave-load (u8: 1 line; bf16: 2 lines).
// NEW (R11): TWO independent nodes interleaved per wave (rows r, r+8) — the
// dual master loop issues ~8 row loads + 2 index vectors per iteration, 2x
// the outstanding misses per wave at identical traffic and per-node
// summation order. Pads (x4) point at the node itself; self term uses
// coefficient (1 - #pads). Output always uint8 + per-row scale.
template<bool IN_U8>
__global__ __launch_bounds__(256, 8) void k_layer(
    const bf16_t* __restrict__ xb,
    const u8* __restrict__ x8, const float* __restrict__ xsc,
    u8* __restrict__ y8, float* __restrict__ ysc,
    const int* __restrict__ poffs, const int* __restrict__ csr,
    const int* __restrict__ deg,
    const float* __restrict__ scale, const float* __restrict__ shift,
    const bf16_t* __restrict__ w1s, const bf16_t* __restrict__ w2s,
    const float* __restrict__ b1, const float* __restrict__ b2,
    float* __restrict__ stats)
{
    __shared__ __align__(16) bf16_t tile[64 * 136];

    const int tid  = threadIdx.x;
    const int w    = tid >> 6;
    const int lane = tid & 63;
    const int base = blockIdx.x * 64;
    const int fb   = lane << 1;          // feature pair
    const int fb2  = fb << 1;            // byte offset in bf16 row

    const float sc0 = scale[fb], sc1 = scale[fb + 1];
    const float sh0 = shift[fb], sh1 = shift[fb + 1];

    // ---- Phase 1: dual-node interleaved gather -> tile ----
    for (int rp = 0; rp < 8; ++rp) {
        const int rowA = (w << 4) + rp;
        const int rowB = rowA + 8;
        const int nA = base + rowA;
        const int nB = base + rowB;
        const bool vA = (nA < N_NODES);
        const bool vB = (nB < N_NODES);
        float a0A = 0.f, a1A = 0.f, a0B = 0.f, a1B = 0.f;
        int eA = 0, eEA = 0, eB = 0, eEB = 0;
        if (vA) { eA = poffs[nA]; eEA = poffs[nA + 1]; }
        if (vB) { eB = poffs[nB]; eEB = poffs[nB + 1]; }

        // dual master loop: 8 edges (4 per node) in flight
        while ((eA < eEA) & (eB < eEB)) {
            int4 qA = *(const int4*)(csr + eA);
            int4 qB = *(const int4*)(csr + eB);
            if (IN_U8) {
                u32 uA0 = *(const unsigned short*)(x8 + ((size_t)qA.x << 7) + fb);
                u32 uA1 = *(const unsigned short*)(x8 + ((size_t)qA.y << 7) + fb);
                u32 uA2 = *(const unsigned short*)(x8 + ((size_t)qA.z << 7) + fb);
                u32 uA3 = *(const unsigned short*)(x8 + ((size_t)qA.w << 7) + fb);
                u32 uB0 = *(const unsigned short*)(x8 + ((size_t)qB.x << 7) + fb);
                u32 uB1 = *(const unsigned short*)(x8 + ((size_t)qB.y << 7) + fb);
                u32 uB2 = *(const unsigned short*)(x8 + ((size_t)qB.z << 7) + fb);
                u32 uB3 = *(const unsigned short*)(x8 + ((size_t)qB.w << 7) + fb);
                float sA0 = xsc[qA.x], sA1 = xsc[qA.y], sA2 = xsc[qA.z], sA3 = xsc[qA.w];
                float sB0 = xsc[qB.x], sB1 = xsc[qB.y], sB2 = xsc[qB.z], sB3 = xsc[qB.w];
                a0A += sA0 * (float)(uA0 & 0xffu); a1A += sA0 * (float)(uA0 >> 8);
                a0A += sA1 * (float)(uA1 & 0xffu); a1A += sA1 * (float)(uA1 >> 8);
                a0A += sA2 * (float)(uA2 & 0xffu); a1A += sA2 * (float)(uA2 >> 8);
                a0A += sA3 * (float)(uA3 & 0xffu); a1A += sA3 * (float)(uA3 >> 8);
                a0B += sB0 * (float)(uB0 & 0xffu); a1B += sB0 * (float)(uB0 >> 8);
                a0B += sB1 * (float)(uB1 & 0xffu); a1B += sB1 * (float)(uB1 >> 8);
                a0B += sB2 * (float)(uB2 & 0xffu); a1B += sB2 * (float)(uB2 >> 8);
                a0B += sB3 * (float)(uB3 & 0xffu); a1B += sB3 * (float)(uB3 >> 8);
            } else {
                u32 vA0 = *(const u32*)((const u8*)xb + ((size_t)qA.x << 8) + fb2);
                u32 vA1 = *(const u32*)((const u8*)xb + ((size_t)qA.y << 8) + fb2);
                u32 vA2 = *(const u32*)((const u8*)xb + ((size_t)qA.z << 8) + fb2);
                u32 vA3 = *(const u32*)((const u8*)xb + ((size_t)qA.w << 8) + fb2);
                u32 vB0 = *(const u32*)((const u8*)xb + ((size_t)qB.x << 8) + fb2);
                u32 vB1 = *(const u32*)((const u8*)xb + ((size_t)qB.y << 8) + fb2);
                u32 vB2 = *(const u32*)((const u8*)xb + ((size_t)qB.z << 8) + fb2);
                u32 vB3 = *(const u32*)((const u8*)xb + ((size_t)qB.w << 8) + fb2);
                a0A += bflo2f(vA0) + bflo2f(vA1) + bflo2f(vA2) + bflo2f(vA3);
                a1A += bfhi2f(vA0) + bfhi2f(vA1) + bfhi2f(vA2) + bfhi2f(vA3);
                a0B += bflo2f(vB0) + bflo2f(vB1) + bflo2f(vB2) + bflo2f(vB3);
                a1B += bfhi2f(vB0) + bfhi2f(vB1) + bfhi2f(vB2) + bfhi2f(vB3);
            }
            eA += 4; eB += 4;
        }
        // drain A
        while (eA < eEA) {
            int4 q = *(const int4*)(csr + eA);
            if (IN_U8) {
                u32 u0 = *(const unsigned short*)(x8 + ((size_t)q.x << 7) + fb);
                u32 u1 = *(const unsigned short*)(x8 + ((size_t)q.y << 7) + fb);
                u32 u2 = *(const unsigned short*)(x8 + ((size_t)q.z << 7) + fb);
                u32 u3 = *(const unsigned short*)(x8 + ((size_t)q.w << 7) + fb);
                float s0 = xsc[q.x], s1 = xsc[q.y], s2 = xsc[q.z], s3 = xsc[q.w];
                a0A += s0 * (float)(u0 & 0xffu); a1A += s0 * (float)(u0 >> 8);
                a0A += s1 * (float)(u1 & 0xffu); a1A += s1 * (float)(u1 >> 8);
                a0A += s2 * (float)(u2 & 0xffu); a1A += s2 * (float)(u2 >> 8);
                a0A += s3 * (float)(u3 & 0xffu); a1A += s3 * (float)(u3 >> 8);
            } else {
                u32 v0 = *(const u32*)((const u8*)xb + ((size_t)q.x << 8) + fb2);
                u32 v1 = *(const u32*)((const u8*)xb + ((size_t)q.y << 8) + fb2);
                u32 v2 = *(const u32*)((const u8*)xb + ((size_t)q.z << 8) + fb2);
                u32 v3 = *(const u32*)((const u8*)xb + ((size_t)q.w << 8) + fb2);
                a0A += bflo2f(v0) + bflo2f(v1) + bflo2f(v2) + bflo2f(v3);
                a1A += bfhi2f(v0) + bfhi2f(v1) + bfhi2f(v2) + bfhi2f(v3);
            }
            eA += 4;
        }
        // drain B
        while (eB < eEB) {
            int4 q = *(const int4*)(csr + eB);
            if (IN_U8) {
                u32 u0 = *(const unsigned short*)(x8 + ((size_t)q.x << 7) + fb);
                u32 u1 = *(const unsigned short*)(x8 + ((size_t)q.y << 7) + fb);
                u32 u2 = *(const unsigned short*)(x8 + ((size_t)q.z << 7) + fb);
                u32 u3 = *(const unsigned short*)(x8 + ((size_t)q.w << 7) + fb);
                float s0 = xsc[q.x], s1 = xsc[q.y], s2 = xsc[q.z], s3 = xsc[q.w];
                a0B += s0 * (float)(u0 & 0xffu); a1B += s0 * (float)(u0 >> 8);
                a0B += s1 * (float)(u1 & 0xffu); a1B += s1 * (float)(u1 >> 8);
                a0B += s2 * (float)(u2 & 0xffu); a1B += s2 * (float)(u2 >> 8);
                a0B += s3 * (float)(u3 & 0xffu); a1B += s3 * (float)(u3 >> 8);
            } else {
                u32 v0 = *(const u32*)((const u8*)xb + ((size_t)q.x << 8) + fb2);
                u32 v1 = *(const u32*)((const u8*)xb + ((size_t)q.y << 8) + fb2);
                u32 v2 = *(const u32*)((const u8*)xb + ((size_t)q.z << 8) + fb2);
                u32 v3 = *(const u32*)((const u8*)xb + ((size_t)q.w << 8) + fb2);
                a0B += bflo2f(v0) + bflo2f(v1) + bflo2f(v2) + bflo2f(v3);
                a1B += bfhi2f(v0) + bfhi2f(v1) + bfhi2f(v2) + bfhi2f(v3);
            }
            eB += 4;
        }
        // finalize A
        if (vA) {
            int dg = deg[nA];
            float selfco = 1.f - (float)(((dg + 3) & ~3) - dg);
            if (IN_U8) {
                u32 sv = *(const unsigned short*)(x8 + ((size_t)nA << 7) + fb);
                float ssv = selfco * xsc[nA];
                a0A += ssv * (float)(sv & 0xffu); a1A += ssv * (float)(sv >> 8);
            } else {
                u32 sv = *(const u32*)((const u8*)xb + ((size_t)nA << 8) + fb2);
                a0A += selfco * bflo2f(sv); a1A += selfco * bfhi2f(sv);
            }
            float cnt = (float)(dg + 1);
            bf16x2 pk;
            pk.x = (bf16_t)(a0A * sc0 + cnt * sh0);
            pk.y = (bf16_t)(a1A * sc1 + cnt * sh1);
            *(bf16x2*)(&tile[rowA * 136 + fb]) = pk;
        } else {
            bf16x2 z; z.x = (bf16_t)0.f; z.y = (bf16_t)0.f;
            *(bf16x2*)(&tile[rowA * 136 + fb]) = z;
        }
        // finalize B
        if (vB) {
            int dg = deg[nB];
            float selfco = 1.f - (float)(((dg + 3) & ~3) - dg);
            if (IN_U8) {
                u32 sv = *(const unsigned short*)(x8 + ((size_t)nB << 7) + fb);
                float ssv = selfco * xsc[nB];
                a0B += ssv * (float)(sv & 0xffu); a1B += ssv * (float)(sv >> 8);
            } else {
                u32 sv = *(const u32*)((const u8*)xb + ((size_t)nB << 8) + fb2);
                a0B += selfco * bflo2f(sv); a1B += selfco * bfhi2f(sv);
            }
            float cnt = (float)(dg + 1);
            bf16x2 pk;
            pk.x = (bf16_t)(a0B * sc0 + cnt * sh0);
            pk.y = (bf16_t)(a1B * sc1 + cnt * sh1);
            *(bf16x2*)(&tile[rowB * 136 + fb]) = pk;
        } else {
            bf16x2 z; z.x = (bf16_t)0.f; z.y = (bf16_t)0.f;
            *(bf16x2*)(&tile[rowB * 136 + fb]) = z;
        }
    }
    __syncthreads();

    // ---- Phase 2: GEMM1 + bias + relu -> tile (reused) ----
    const int q = lane >> 4;
    const int c16 = lane & 15;
    const int arow = (w << 4) + c16;

    bf16x8 afr[4];
#pragma unroll
    for (int ks = 0; ks < 4; ++ks)
        afr[ks] = *(const bf16x8*)(&tile[arow * 136 + ks * 32 + q * 8]);
    __syncthreads();

    f32x4 acc[8];
#pragma unroll
    for (int nt = 0; nt < 8; ++nt) acc[nt] = (f32x4){0.f, 0.f, 0.f, 0.f};
#pragma unroll
    for (int ks = 0; ks < 4; ++ks) {
#pragma unroll
        for (int nt = 0; nt < 8; ++nt) {
            bf16x8 bfr = *(const bf16x8*)(w1s + (((ks << 3) + nt) * 64 + lane) * 8);
            acc[nt] = __builtin_amdgcn_mfma_f32_16x16x32_bf16(afr[ks], bfr, acc[nt], 0, 0, 0);
        }
    }
#pragma unroll
    for (int nt = 0; nt < 8; ++nt) {
        float bias = b1[(nt << 4) + c16];
#pragma unroll
        for (int i = 0; i < 4; ++i) {
            float v = fmaxf(acc[nt][i] + bias, 0.f);
            int row = (w << 4) + (q << 2) + i;
            tile[row * 136 + (nt << 4) + c16] = (bf16_t)v;
        }
    }
    __syncthreads();

    // ---- Phase 3: GEMM2 + bias + relu + BN stats -> tile ----
    bf16x8 afr2[4];
#pragma unroll
    for (int ks = 0; ks < 4; ++ks)
        afr2[ks] = *(const bf16x8*)(&tile[arow * 136 + ks * 32 + q * 8]);
    __syncthreads(); // tile overwritten below

#pragma unroll
    for (int nt = 0; nt < 8; ++nt) acc[nt] = (f32x4){0.f, 0.f, 0.f, 0.f};
#pragma unroll
    for (int ks = 0; ks < 4; ++ks) {
#pragma unroll
        for (int nt = 0; nt < 8; ++nt) {
            bf16x8 bfr = *(const bf16x8*)(w2s + (((ks << 3) + nt) * 64 + lane) * 8);
            acc[nt] = __builtin_amdgcn_mfma_f32_16x16x32_bf16(afr2[ks], bfr, acc[nt], 0, 0, 0);
        }
    }
#pragma unroll
    for (int nt = 0; nt < 8; ++nt) {
        float bias = b2[(nt << 4) + c16];
        float s1 = 0.f, s2 = 0.f;
#pragma unroll
        for (int i = 0; i < 4; ++i) {
            float v = fmaxf(acc[nt][i] + bias, 0.f);
            int row = (w << 4) + (q << 2) + i;
            int node = base + row;
            if (node < N_NODES) {
                s1 += v;
                s2 += v * v;
            }
            tile[row * 136 + (nt << 4) + c16] = (bf16_t)v;
        }
        s1 += __shfl_down(s1, 32); s2 += __shfl_down(s2, 32);
        s1 += __shfl_down(s1, 16); s2 += __shfl_down(s2, 16);
        if (lane < 16) {
            atomicAdd(&stats[(nt << 4) + lane], s1);
            atomicAdd(&stats[DD + (nt << 4) + lane], s2);
        }
    }
    __syncthreads();

    // ---- Phase 4: quantize rows -> uint8 + scale. 4 threads per row. ----
    {
        int row4 = tid >> 2, t4 = tid & 3;
        int node = base + row4;
        if (node < N_NODES) {
            const bf16_t* tp = tile + row4 * 136 + t4 * 32;
            bf16x8 v0 = *(const bf16x8*)(tp);
            bf16x8 v1 = *(const bf16x8*)(tp + 8);
            bf16x8 v2 = *(const bf16x8*)(tp + 16);
            bf16x8 v3 = *(const bf16x8*)(tp + 24);
            float am = 0.f;
#pragma unroll
            for (int k = 0; k < 8; ++k) {
                am = fmaxf(am, (float)v0[k]);
                am = fmaxf(am, (float)v1[k]);
                am = fmaxf(am, (float)v2[k]);
                am = fmaxf(am, (float)v3[k]);
            }
            am = fmaxf(am, __shfl_xor(am, 1));
            am = fmaxf(am, __shfl_xor(am, 2));
            float inv = am > 0.f ? 255.f / am : 0.f;
            if (t4 == 0) ysc[node] = am * (1.f / 255.f);
            u32 u[8];
            u[0] = pack4u((float)v0[0], (float)v0[1], (float)v0[2], (float)v0[3], inv);
            u[1] = pack4u((float)v0[4], (float)v0[5], (float)v0[6], (float)v0[7], inv);
            u[2] = pack4u((float)v1[0], (float)v1[1], (float)v1[2], (float)v1[3], inv);
            u[3] = pack4u((float)v1[4], (float)v1[5], (float)v1[6], (float)v1[7], inv);
            u[4] = pack4u((float)v2[0], (float)v2[1], (float)v2[2], (float)v2[3], inv);
            u[5] = pack4u((float)v2[4], (float)v2[5], (float)v2[6], (float)v2[7], inv);
            u[6] = pack4u((float)v3[0], (float)v3[1], (float)v3[2], (float)v3[3], inv);
            u[7] = pack4u((float)v3[4], (float)v3[5], (float)v3[6], (float)v3[7], inv);
            uint4* yp = (uint4*)(y8 + (size_t)node * DD + t4 * 32);
            yp[0] = make_uint4(u[0], u[1], u[2], u[3]);
            yp[1] = make_uint4(u[4], u[5], u[6], u[7]);
        }
    }
}

// ---------------- pooling + head ----------------

// dequantizing segmented mean-pool, 2 nodes in flight per block
__global__ __launch_bounds__(256) void k_pool2u(
    const u8* __restrict__ y8, const float* __restrict__ ysc,
    const int* __restrict__ gstart,
    const float* __restrict__ scale, const float* __restrict__ shift,
    float* __restrict__ pooled)
{
    __shared__ float part[128];
    int g = blockIdx.x;
    int t = threadIdx.x;
    int f = t & 127, h = t >> 7;
    int s = gstart[g], e = gstart[g + 1];
    float acc = 0.f;
    for (int n = s + h; n < e; n += 2)
        acc += ysc[n] * (float)y8[(size_t)n * DD + f];
    if (h == 1) part[f] = acc;
    __syncthreads();
    if (h == 0) {
        acc += part[f];
        float cnt = (float)(e - s);
        float v = acc * scale[f] + cnt * shift[f];
        pooled[g * DD + f] = v / fmaxf(cnt, 1.0f);
    }
}

__global__ void k_head(const float* __restrict__ pooled,
                       const float* __restrict__ lin1w, const float* __restrict__ lin1b,
                       const float* __restrict__ lin2w, const float* __restrict__ lin2b,
                       float* __restrict__ out) {
    __shared__ float p[DD];
    __shared__ float h[DD];
    int g = blockIdx.x;
    int t = threadIdx.x;
    p[t] = pooled[g * DD + t];
    __syncthreads();
    float a = lin1b[t];
    for (int k = 0; k < DD; ++k) a += p[k] * lin1w[k * DD + t];
    h[t] = fmaxf(a, 0.f);
    __syncthreads();
    if (t < 10) {
        float o = lin2b[t];
        for (int k = 0; k < DD; ++k) o += h[k] * lin2w[k * 10 + t];
        out[g * 10 + t] = o;
    }
}

// ---------------- launch ----------------

extern "C" void kernel_launch(void* const* d_in, const int* in_sizes, int n_in,
                              void* d_out, int out_size, void* d_ws, size_t ws_size,
                              hipStream_t stream) {
    const float* x      = (const float*)d_in[0];
    const int*   ei     = (const int*)d_in[1];
    const int*   batch  = (const int*)d_in[2];
    const float* W1s    = (const float*)d_in[3];
    const float* b1s    = (const float*)d_in[4];
    const float* W2s    = (const float*)d_in[5];
    const float* b2s    = (const float*)d_in[6];
    const float* gammas = (const float*)d_in[7];
    const float* betas  = (const float*)d_in[8];
    const float* lin1w  = (const float*)d_in[9];
    const float* lin1b  = (const float*)d_in[10];
    const float* lin2w  = (const float*)d_in[11];
    const float* lin2b  = (const float*)d_in[12];
    float* out = (float*)d_out;

    char* p = (char*)d_ws;
    size_t off = 0;
    auto alloc = [&](size_t bytes) -> char* {
        char* r = p + off;
        off += (bytes + 255) & ~(size_t)255;
        return r;
    };
    int*    deg    = (int*)alloc(N_NODES * 4);
    float*  stats  = (float*)alloc(3 * 256 * 4);
    size_t zero_bytes = off;
    int*    poffs  = (int*)alloc((N_NODES + 1) * 4);
    int*    cursor = (int*)alloc(N_NODES * 4);
    int*    bsum   = (int*)alloc(128 * 4);
    int*    bbase  = (int*)alloc(128 * 4);
    int*    csr    = (int*)alloc(((size_t)N_EDGES + 4 * N_NODES + 64) * 4); // pad-4 + slack
    bf16_t* xb     = (bf16_t*)alloc((size_t)N_NODES * DD * 2);  // bf16 input; q8b aliases it after L0
    u8*     q8a    = (u8*)alloc((size_t)N_NODES * DD);
    float*  sca    = (float*)alloc(N_NODES * 4);
    float*  scb    = (float*)alloc(N_NODES * 4);
    bf16_t* wshuf  = (bf16_t*)alloc(6 * 16384 * 2);
    float*  ss     = (float*)alloc(4 * 256 * 4);
    int*    gstart = (int*)alloc((N_GRAPHS + 1) * 4);
    float*  pooled = (float*)alloc(N_GRAPHS * DD * 4);
    if (off > ws_size) return;

    // q8b reuses xb's storage: xb is only read by L0; q8b is written by L1 and
    // read by L2 (stream-ordered on one stream, no overlap). Proven in R10.
    u8* q8b = (u8*)xb;

    const int* srcA = ei;
    const int* dstA = ei + N_EDGES;

    k_zero<<<256, 256, 0, stream>>>((float4*)d_ws, (int)(zero_bytes / 16));
    k_hist<<<1024, 256, 0, stream>>>(dstA, deg);
    k_scan1<<<SCAN_B, 1024, 0, stream>>>(deg, bsum);
    k_scan2<<<1, 128, 0, stream>>>(bsum, bbase, poffs);
    k_scan3<<<SCAN_B, 1024, 0, stream>>>(deg, bbase, poffs, cursor);
    k_fill<<<1024, 256, 0, stream>>>(srcA, dstA, cursor, csr);
    k_pad<<<(N_NODES * 4 + 255) / 256, 256, 0, stream>>>(deg, poffs, csr);
    k_cvt<<<1024, 256, 0, stream>>>(x, xb);
    k_shufw<<<(6 * 16384 + 255) / 256, 256, 0, stream>>>(W1s, W2s, wshuf);
    k_aff_init<<<1, 128, 0, stream>>>(ss);
    k_gbounds<<<(N_NODES + 255) / 256, 256, 0, stream>>>(batch, gstart);

    // L0: xb (bf16) -> q8a. L1: q8a -> q8b (aliases xb). L2: q8b -> q8a.
    k_layer<false><<<NTILES, 256, 0, stream>>>(
        xb, q8a, sca, q8a, sca, poffs, csr, deg,
        ss + 0 * 256, ss + 0 * 256 + 128,
        wshuf + 0 * 16384, wshuf + 1 * 16384,
        b1s + 0 * DD, b2s + 0 * DD, stats + 0 * 256);
    k_aff_update<<<1, 128, 0, stream>>>(stats + 0 * 256, gammas + 0 * DD, betas + 0 * DD,
                                        ss + 1 * 256, ss + 1 * 256 + 128);
    k_layer<true><<<NTILES, 256, 0, stream>>>(
        xb, q8a, sca, q8b, scb, poffs, csr, deg,
        ss + 1 * 256, ss + 1 * 256 + 128,
        wshuf + 2 * 16384, wshuf + 3 * 16384,
        b1s + 1 * DD, b2s + 1 * DD, stats + 1 * 256);
    k_aff_update<<<1, 128, 0, stream>>>(stats + 1 * 256, gammas + 1 * DD, betas + 1 * DD,
                                        ss + 2 * 256, ss + 2 * 256 + 128);
    k_layer<true><<<NTILES, 256, 0, stream>>>(
        xb, q8b, scb, q8a, sca, poffs, csr, deg,
        ss + 2 * 256, ss + 2 * 256 + 128,
        wshuf + 4 * 16384, wshuf + 5 * 16384,
        b1s + 2 * DD, b2s + 2 * DD, stats + 2 * 256);
    k_aff_update<<<1, 128, 0, stream>>>(stats + 2 * 256, gammas + 2 * DD, betas + 2 * DD,
                                        ss + 3 * 256, ss + 3 * 256 + 128);

    k_pool2u<<<N_GRAPHS, 256, 0, stream>>>(q8a, sca, gstart,
                                           ss + 3 * 256, ss + 3 * 256 + 128, pooled);
    k_head<<<N_GRAPHS, 128, 0, stream>>>(pooled, lin1w, lin1b, lin2w, lin2b, out);
}